// Round 9
// baseline (725.450 us; speedup 1.0000x reference)
//
#include <hip/hip_runtime.h>

#define NN 100000   // nodes
#define NE 600000   // edges
#define NG 4096     // graphs
#define FIN 74
#define HD 128
#define NL 3
#define BN_EPS 1e-5f
#define NSCAN 391   // ceil(NN/256)
#define NSTRIPE 64  // bnsum stripes (contention control)

typedef __attribute__((ext_vector_type(8))) short short8;
typedef __attribute__((ext_vector_type(4))) float floatx4;
typedef __attribute__((ext_vector_type(8))) unsigned short bf16x8;  // ushort4/8 collide with HIP headers
typedef __attribute__((ext_vector_type(4))) unsigned short bf16x4;

__device__ __forceinline__ unsigned short f2bf(float f) {
    unsigned u = __float_as_uint(f);
    u += 0x7fff + ((u >> 16) & 1);   // round-to-nearest-even
    return (unsigned short)(u >> 16);
}
__device__ __forceinline__ float bf2f(unsigned short u) {
    return __uint_as_float(((unsigned)u) << 16);
}

// ---------------- CSR build ----------------
__global__ __launch_bounds__(256) void k_hist(const int* __restrict__ dst,
                                              int* __restrict__ degi) {
    int e = blockIdx.x * 256 + threadIdx.x;
    if (e < NE) atomicAdd(&degi[dst[e]], 1);
}

__global__ __launch_bounds__(256) void k_scan1(const int* __restrict__ degi,
                                               int* __restrict__ part) {
    __shared__ int s[256];
    int t = threadIdx.x;
    int idx = blockIdx.x * 256 + t;
    s[t] = (idx < NN) ? degi[idx] : 0;
    __syncthreads();
    for (int off = 128; off > 0; off >>= 1) {
        if (t < off) s[t] += s[t + off];
        __syncthreads();
    }
    if (t == 0) part[blockIdx.x] = s[0];
}

__global__ __launch_bounds__(512) void k_scan2(int* __restrict__ part) {
    __shared__ int s[512];
    int t = threadIdx.x;
    s[t] = (t < NSCAN) ? part[t] : 0;
    __syncthreads();
    for (int off = 1; off < 512; off <<= 1) {
        int v = s[t];
        int a = (t >= off) ? s[t - off] : 0;
        __syncthreads();
        s[t] = v + a;
        __syncthreads();
    }
    if (t < NSCAN) part[t] = (t > 0) ? s[t - 1] : 0;  // exclusive
}

// scan3 + dinv fused
__global__ __launch_bounds__(256) void k_scan3(const int* __restrict__ degi,
                                               const int* __restrict__ part,
                                               int* __restrict__ rowptr,
                                               float* __restrict__ dinv) {
    __shared__ int s[256];
    int t = threadIdx.x;
    int idx = blockIdx.x * 256 + t;
    int v = (idx < NN) ? degi[idx] : 0;
    s[t] = v;
    __syncthreads();
    for (int off = 1; off < 256; off <<= 1) {
        int x = s[t];
        int a = (t >= off) ? s[t - off] : 0;
        __syncthreads();
        s[t] = x + a;
        __syncthreads();
    }
    if (idx < NN) {
        rowptr[idx] = part[blockIdx.x] + (s[t] - v);
        dinv[idx] = rsqrtf((float)v + 1.0f);  // +1 self-loop
    }
    if (idx == 0) rowptr[NN] = NE;
}

__global__ __launch_bounds__(256) void k_fill(const int* __restrict__ src,
                                              const int* __restrict__ dst,
                                              const int* __restrict__ rowptr,
                                              int* __restrict__ cursor,
                                              int* __restrict__ col) {
    int e = blockIdx.x * 256 + threadIdx.x;
    if (e >= NE) return;
    int d = dst[e];
    int pos = rowptr[d] + atomicAdd(&cursor[d], 1);
    col[pos] = src[e];
}

// ---------------- graph boundaries from sorted batch ----------------
__global__ __launch_bounds__(256) void k_bounds(const int* __restrict__ batch,
                                                int* __restrict__ gstart) {
    int n = blockIdx.x * 256 + threadIdx.x;
    if (n >= NN) return;
    int b = batch[n];
    int bp = (n == 0) ? -1 : batch[n - 1];
    for (int g = bp + 1; g <= b; g++) gstart[g] = n;
    if (n == NN - 1)
        for (int g = b + 1; g <= NG; g++) gstart[g] = NN;
}

// ---------------- weight fragment pre-pack (bf16), emb + conv fused ----------------
__global__ __launch_bounds__(256) void k_wpack(const float* __restrict__ embW,
                                               const float* __restrict__ convW,
                                               unsigned short* __restrict__ WfE,
                                               unsigned short* __restrict__ WfC) {
    int d = blockIdx.x * 256 + threadIdx.x;
    if (d < 12288) {
        int inner = d & 511, outer = d >> 9;
        int kstep = outer % 3, nt = outer / 3;
        int g = inner >> 7, n = (inner >> 3) & 15, j = inner & 7;
        int k = kstep * 32 + g * 8 + j;
        float v = (k < FIN) ? embW[k * HD + nt * 16 + n] : 0.0f;
        WfE[d] = f2bf(v);
    } else {
        int e = d - 12288;
        if (e >= NL * 16384) return;
        int layer = e >> 14, r = e & 16383;
        int j = r & 7, n = (r >> 3) & 15, g = (r >> 7) & 3, kstep = (r >> 9) & 3, nt = r >> 11;
        int k = kstep * 32 + g * 8 + j;
        WfC[e] = f2bf(convW[layer * 16384 + k * HD + nt * 16 + n]);
    }
}

// ---------------- embedding MFMA: A = relu(x @ W + b), bf16 out ----------------
__global__ __launch_bounds__(256) void k_emb(const float* __restrict__ x,
                                             const unsigned short* __restrict__ Wf,
                                             const float* __restrict__ b,
                                             unsigned short* __restrict__ hA) {
    __shared__ __align__(16) unsigned short As[4224];
    int t = threadIdx.x;
    int n0 = blockIdx.x * 32;
    for (int f = t; f < 3072; f += 256) {
        int m = f / 96, kp = f % 96;
        float v = (kp < FIN) ? x[(n0 + m) * FIN + kp] : 0.0f;
        int kstep = kp >> 5, g = (kp >> 3) & 3, j = kp & 7;
        As[(kstep * 4 + g) * 264 + m * 8 + j] = f2bf(v);
    }
    __syncthreads();
    int lane = t & 63, wv = t >> 6;
    int lanelo = lane & 15, g = lane >> 4;
    floatx4 acc[2][2] = {};
#pragma unroll
    for (int kstep = 0; kstep < 3; kstep++) {
        short8 a0 = *(const short8*)&As[(kstep * 4 + g) * 264 + lanelo * 8];
        short8 a1 = *(const short8*)&As[(kstep * 4 + g) * 264 + 128 + lanelo * 8];
        short8 b0 = *(const short8*)&Wf[(((wv * 2 + 0) * 3 + kstep) * 4 + g) * 128 + lanelo * 8];
        short8 b1 = *(const short8*)&Wf[(((wv * 2 + 1) * 3 + kstep) * 4 + g) * 128 + lanelo * 8];
        acc[0][0] = __builtin_amdgcn_mfma_f32_16x16x32_bf16(a0, b0, acc[0][0], 0, 0, 0);
        acc[0][1] = __builtin_amdgcn_mfma_f32_16x16x32_bf16(a0, b1, acc[0][1], 0, 0, 0);
        acc[1][0] = __builtin_amdgcn_mfma_f32_16x16x32_bf16(a1, b0, acc[1][0], 0, 0, 0);
        acc[1][1] = __builtin_amdgcn_mfma_f32_16x16x32_bf16(a1, b1, acc[1][1], 0, 0, 0);
    }
    __syncthreads();  // reuse As as output tile (stride 132)
#pragma unroll
    for (int ns = 0; ns < 2; ns++) {
        int colc = wv * 32 + ns * 16 + lanelo;
        float bias = b[colc];
#pragma unroll
        for (int ms = 0; ms < 2; ms++)
#pragma unroll
            for (int r = 0; r < 4; r++) {
                int rowl = ms * 16 + g * 4 + r;
                As[rowl * 132 + colc] = f2bf(fmaxf(acc[ms][ns][r] + bias, 0.0f));
            }
    }
    __syncthreads();
#pragma unroll
    for (int i = 0; i < 2; i++) {
        int f = t * 8 + i * 2048;
        int m = f >> 7, c = f & 127;
        bf16x4 lo = *(const bf16x4*)&As[m * 132 + c];
        bf16x4 hi = *(const bf16x4*)&As[m * 132 + c + 4];
        bf16x8 o = {lo.x, lo.y, lo.z, lo.w, hi.x, hi.y, hi.z, hi.w};
        *(bf16x8*)&hA[n0 * HD + f] = o;
    }
}

// ---------------- conv MFMA: B' = (act(A) @ W) * dinv[row], bf16 in/out ----------------
template <bool BN>
__global__ __launch_bounds__(256) void k_conv(const unsigned short* __restrict__ hin,
                                              const float* __restrict__ ss,
                                              const unsigned short* __restrict__ Wf,
                                              const float* __restrict__ dinv,
                                              unsigned short* __restrict__ hw) {
    __shared__ __align__(16) unsigned short As[4224];
    __shared__ float dinvs[32];
    int t = threadIdx.x;
    int n0 = blockIdx.x * 32;
    if (t < 32) dinvs[t] = dinv[n0 + t];
    int f0 = t * 8;
    int k0 = f0 & 127;
    float sc[8], sh[8];
    if (BN) {
        floatx4 s0 = *(const floatx4*)&ss[k0];
        floatx4 s1 = *(const floatx4*)&ss[k0 + 4];
        floatx4 h0 = *(const floatx4*)&ss[HD + k0];
        floatx4 h1 = *(const floatx4*)&ss[HD + k0 + 4];
        sc[0] = s0.x; sc[1] = s0.y; sc[2] = s0.z; sc[3] = s0.w;
        sc[4] = s1.x; sc[5] = s1.y; sc[6] = s1.z; sc[7] = s1.w;
        sh[0] = h0.x; sh[1] = h0.y; sh[2] = h0.z; sh[3] = h0.w;
        sh[4] = h1.x; sh[5] = h1.y; sh[6] = h1.z; sh[7] = h1.w;
    }
    int combo = (k0 >> 5) * 4 + ((k0 >> 3) & 3);
#pragma unroll
    for (int i = 0; i < 2; i++) {
        int f = f0 + i * 2048;
        int m = f >> 7;
        bf16x8 u = *(const bf16x8*)&hin[n0 * HD + f];
        bf16x8 o;
        if (BN) {
#pragma unroll
            for (int jj = 0; jj < 8; jj++) {
                float v = fmaxf(bf2f(u[jj]) * sc[jj] + sh[jj], 0.0f);
                o[jj] = f2bf(v);
            }
        } else {
            o = u;
        }
        *(bf16x8*)&As[combo * 264 + m * 8] = o;
    }
    __syncthreads();
    int lane = t & 63, wv = t >> 6;
    int lanelo = lane & 15, g = lane >> 4;
    floatx4 acc[2][2] = {};
#pragma unroll
    for (int ks = 0; ks < 4; ks++) {
        short8 a0 = *(const short8*)&As[(ks * 4 + g) * 264 + lanelo * 8];
        short8 a1 = *(const short8*)&As[(ks * 4 + g) * 264 + 128 + lanelo * 8];
        short8 b0 = *(const short8*)&Wf[(((wv * 2 + 0) * 4 + ks) * 4 + g) * 128 + lanelo * 8];
        short8 b1 = *(const short8*)&Wf[(((wv * 2 + 1) * 4 + ks) * 4 + g) * 128 + lanelo * 8];
        acc[0][0] = __builtin_amdgcn_mfma_f32_16x16x32_bf16(a0, b0, acc[0][0], 0, 0, 0);
        acc[0][1] = __builtin_amdgcn_mfma_f32_16x16x32_bf16(a0, b1, acc[0][1], 0, 0, 0);
        acc[1][0] = __builtin_amdgcn_mfma_f32_16x16x32_bf16(a1, b0, acc[1][0], 0, 0, 0);
        acc[1][1] = __builtin_amdgcn_mfma_f32_16x16x32_bf16(a1, b1, acc[1][1], 0, 0, 0);
    }
    __syncthreads();  // reuse As as output tile
#pragma unroll
    for (int ms = 0; ms < 2; ms++)
#pragma unroll
        for (int ns = 0; ns < 2; ns++) {
            int colc = wv * 32 + ns * 16 + lanelo;
#pragma unroll
            for (int r = 0; r < 4; r++) {
                int rowl = ms * 16 + g * 4 + r;
                As[rowl * 132 + colc] = f2bf(acc[ms][ns][r] * dinvs[rowl]);
            }
        }
    __syncthreads();
#pragma unroll
    for (int i = 0; i < 2; i++) {
        int f = f0 + i * 2048;
        int m = f >> 7, c = f & 127;
        bf16x4 lo = *(const bf16x4*)&As[m * 132 + c];
        bf16x4 hi = *(const bf16x4*)&As[m * 132 + c + 4];
        bf16x8 o = {lo.x, lo.y, lo.z, lo.w, hi.x, hi.y, hi.z, hi.w};
        *(bf16x8*)&hw[n0 * HD + f] = o;
    }
}

// ---------------- CSR gather + fused BN-stats ----------------
// A[n] = (B'[n] + sum_in B'[s]) * dinv[n] + bias; per-channel sum/sumsq -> bnsum stripe
__global__ __launch_bounds__(256) void k_gather(const int* __restrict__ rowptr,
                                                const int* __restrict__ col,
                                                const float* __restrict__ dinv,
                                                const unsigned short* __restrict__ B,
                                                const float* __restrict__ bias,
                                                unsigned short* __restrict__ A,
                                                float* __restrict__ bnsum) {
    __shared__ float ls[256];
    int t = threadIdx.x;
    ls[t] = 0.0f;
    int n = blockIdx.x * 16 + (t >> 4);  // 16 nodes/block, 16 lanes/node
    int c8 = (t & 15) * 8;
    bf16x8 u = *(const bf16x8*)&B[n * HD + c8];
    float acc[8];
#pragma unroll
    for (int i = 0; i < 8; i++) acc[i] = bf2f(u[i]);
    int j0 = rowptr[n], j1 = rowptr[n + 1];
    int j = j0;
    for (; j + 3 < j1; j += 4) {   // 4 edges in flight
        int s0 = col[j], s1 = col[j + 1], s2 = col[j + 2], s3 = col[j + 3];
        bf16x8 v0 = *(const bf16x8*)&B[s0 * HD + c8];
        bf16x8 v1 = *(const bf16x8*)&B[s1 * HD + c8];
        bf16x8 v2 = *(const bf16x8*)&B[s2 * HD + c8];
        bf16x8 v3 = *(const bf16x8*)&B[s3 * HD + c8];
#pragma unroll
        for (int i = 0; i < 8; i++)
            acc[i] += (bf2f(v0[i]) + bf2f(v1[i])) + (bf2f(v2[i]) + bf2f(v3[i]));
    }
    for (; j < j1; j++) {
        int s = col[j];
        bf16x8 v = *(const bf16x8*)&B[s * HD + c8];
#pragma unroll
        for (int i = 0; i < 8; i++) acc[i] += bf2f(v[i]);
    }
    float dd = dinv[n];
    floatx4 b0 = *(const floatx4*)&bias[c8];
    floatx4 b1 = *(const floatx4*)&bias[c8 + 4];
    float hv[8];
    hv[0] = acc[0] * dd + b0.x; hv[1] = acc[1] * dd + b0.y;
    hv[2] = acc[2] * dd + b0.z; hv[3] = acc[3] * dd + b0.w;
    hv[4] = acc[4] * dd + b1.x; hv[5] = acc[5] * dd + b1.y;
    hv[6] = acc[6] * dd + b1.z; hv[7] = acc[7] * dd + b1.w;
    bf16x8 o;
#pragma unroll
    for (int i = 0; i < 8; i++) o[i] = f2bf(hv[i]);
    *(bf16x8*)&A[n * HD + c8] = o;
    // BN statistics: LDS block-reduce then one striped global atomic per thread
    __syncthreads();   // ls zero-init visible
#pragma unroll
    for (int i = 0; i < 8; i++) {
        atomicAdd(&ls[c8 + i], hv[i]);
        atomicAdd(&ls[HD + c8 + i], hv[i] * hv[i]);
    }
    __syncthreads();
    atomicAdd(&bnsum[(blockIdx.x & (NSTRIPE - 1)) * 256 + t], ls[t]);
}

// ---------------- BN finalize: reduce 64 stripes -> scale/shift ----------------
__global__ __launch_bounds__(128) void k_bn_fin(const float* __restrict__ bnsum,
                                                const float* __restrict__ gamma,
                                                const float* __restrict__ beta,
                                                float* __restrict__ ss) {
    int c = threadIdx.x;
    float s = 0.0f, sq = 0.0f;
    for (int i = 0; i < NSTRIPE; i++) {
        s  += bnsum[i * 256 + c];
        sq += bnsum[i * 256 + HD + c];
    }
    float inv_n = 1.0f / (float)NN;
    float mu = s * inv_n;
    float var = sq * inv_n - mu * mu;
    float sc = gamma[c] * rsqrtf(var + BN_EPS);
    ss[c] = sc;
    ss[HD + c] = beta[c] - mu * sc;
}

// ---------------- atomic-free pooling: one block per graph (float gfeat out) ----------------
__global__ __launch_bounds__(128) void k_pool_g(const unsigned short* __restrict__ h,
                                                const float* __restrict__ ss,
                                                const int* __restrict__ gstart,
                                                float* __restrict__ gfeat) {
    int g = blockIdx.x;
    int c = threadIdx.x;
    int n0 = gstart[g], n1 = gstart[g + 1];
    float sc = ss[c], sh = ss[HD + c];
    float s = 0.0f, mx = 0.0f;   // post-ReLU >= 0; 0 matches empty-seg guard
    for (int n = n0; n < n1; n++) {
        float v = fmaxf(bf2f(h[n * HD + c]) * sc + sh, 0.0f);
        s += v;
        mx = fmaxf(mx, v);
    }
    float cntf = (float)(n1 - n0);
    gfeat[g * 256 + c] = s / fmaxf(cntf, 1.0f);
    gfeat[g * 256 + HD + c] = mx;
}

// ---------------- MLP head v2: 8 graphs/block, 256 threads, split-K ----------------
__global__ __launch_bounds__(256) void k_mlp(const float* __restrict__ gfeat,
                                             const float* __restrict__ w1,
                                             const float* __restrict__ b1,
                                             const float* __restrict__ w2,
                                             const float* __restrict__ b2,
                                             const float* __restrict__ w3,
                                             const float* __restrict__ b3,
                                             float* __restrict__ out) {
    __shared__ float gs[8][258];
    __shared__ float p1[8][130];
    __shared__ float hs[8][130];
    __shared__ float p2[3][8][66];
    __shared__ float h2s[8][66];
    __shared__ float ps[64];
    int t = threadIdx.x;
    int g0 = blockIdx.x * 8;
    for (int f = t; f < 2048; f += 256) {
        int gi = f >> 8, k = f & 255;
        gs[gi][k] = gfeat[(g0 + gi) * 256 + k];
    }
    __syncthreads();
    {
        int colc = t & 127, half = t >> 7;
        int kb = half * 128;
        float acc[8] = {};
        for (int k = 0; k < 128; k++) {
            float w = w1[(kb + k) * HD + colc];
#pragma unroll
            for (int gi = 0; gi < 8; gi++) acc[gi] += gs[gi][kb + k] * w;
        }
        if (half == 1) {
#pragma unroll
            for (int gi = 0; gi < 8; gi++) p1[gi][colc] = acc[gi];
        }
        __syncthreads();
        if (half == 0) {
            float bias = b1[colc];
#pragma unroll
            for (int gi = 0; gi < 8; gi++)
                hs[gi][colc] = fmaxf(acc[gi] + p1[gi][colc] + bias, 0.0f);
        }
    }
    __syncthreads();
    {
        int colc = t & 63, q = t >> 6;
        int kb = q * 32;
        float acc[8] = {};
        for (int k = 0; k < 32; k++) {
            float w = w2[(kb + k) * 64 + colc];
#pragma unroll
            for (int gi = 0; gi < 8; gi++) acc[gi] += hs[gi][kb + k] * w;
        }
        if (q > 0) {
#pragma unroll
            for (int gi = 0; gi < 8; gi++) p2[q - 1][gi][colc] = acc[gi];
        }
        __syncthreads();
        if (q == 0) {
            float bias = b2[colc];
#pragma unroll
            for (int gi = 0; gi < 8; gi++)
                h2s[gi][colc] = fmaxf(acc[gi] + p2[0][gi][colc] + p2[1][gi][colc]
                                      + p2[2][gi][colc] + bias, 0.0f);
        }
    }
    __syncthreads();
    if (t < 64) {
        int gi = t >> 3, prt = t & 7;
        float p = 0.0f;
#pragma unroll
        for (int k = 0; k < 8; k++) p += h2s[gi][prt * 8 + k] * w3[prt * 8 + k];
        ps[t] = p;
    }
    __syncthreads();
    if (t < 8) {
        float a = b3[0];
#pragma unroll
        for (int i = 0; i < 8; i++) a += ps[t * 8 + i];
        out[g0 + t] = a;
    }
}

extern "C" void kernel_launch(void* const* d_in, const int* in_sizes, int n_in,
                              void* d_out, int out_size, void* d_ws, size_t ws_size,
                              hipStream_t stream) {
    const float* x      = (const float*)d_in[0];
    const int*   eidx   = (const int*)d_in[1];   // [2, NE]: src then dst
    const int*   batch  = (const int*)d_in[2];
    const float* emb_W  = (const float*)d_in[3];
    const float* emb_b  = (const float*)d_in[4];
    const float* conv_W = (const float*)d_in[5];
    const float* conv_b = (const float*)d_in[6];
    const float* gamma  = (const float*)d_in[7];
    const float* beta   = (const float*)d_in[8];
    const float* w1     = (const float*)d_in[9];
    const float* b1     = (const float*)d_in[10];
    const float* w2     = (const float*)d_in[11];
    const float* b2     = (const float*)d_in[12];
    const float* w3     = (const float*)d_in[13];
    const float* b3     = (const float*)d_in[14];
    float* out = (float*)d_out;

    const int* src = eidx;
    const int* dst = eidx + NE;

    // workspace carve-up — bnsum3 / degi / cursor contiguous for ONE zeroing memset
    unsigned short* A = (unsigned short*)d_ws;       // [NN*HD] bf16
    unsigned short* B = A + NN * HD;                 // [NN*HD] bf16
    float* dinv  = (float*)(B + NN * HD);            // [NN]
    float* bnss  = dinv + NN;                        // [256]
    float* gfeat = bnss + 256;                       // [NG*256] float
    float* bnsum3= gfeat + NG * 256;                 // [NL*NSTRIPE*256]  (zeroed)
    int*   degi  = (int*)(bnsum3 + NL * NSTRIPE * 256); // [NN]            (zeroed)
    int*   cursor= degi + NN;                        // [NN]              (zeroed)
    int*   gstart= cursor + NN;                      // [NG+1]
    int*   rowptr= gstart + NG + 1;                  // [NN+1]
    int*   part  = rowptr + NN + 1;                  // [NSCAN]
    int*   col   = part + NSCAN;                     // [NE]
    unsigned short* WfE = (unsigned short*)(col + NE);  // [12288]
    unsigned short* WfC = WfE + 12288;                  // [3*16384]

    // ---- single zeroing memset: bnsum3 + degi + cursor ----
    (void)hipMemsetAsync(bnsum3, 0,
                         (NL * NSTRIPE * 256) * sizeof(float) + 2 * NN * sizeof(int),
                         stream);
    k_hist<<<(NE + 255) / 256, 256, 0, stream>>>(dst, degi);
    k_scan1<<<NSCAN, 256, 0, stream>>>(degi, part);
    k_scan2<<<1, 512, 0, stream>>>(part);
    k_scan3<<<NSCAN, 256, 0, stream>>>(degi, part, rowptr, dinv);
    k_fill<<<(NE + 255) / 256, 256, 0, stream>>>(src, dst, rowptr, cursor, col);
    k_bounds<<<(NN + 255) / 256, 256, 0, stream>>>(batch, gstart);
    k_wpack<<<240, 256, 0, stream>>>(emb_W, conv_W, WfE, WfC);

    // ---- embedding (bf16 out) ----
    k_emb<<<NN / 32, 256, 0, stream>>>(x, WfE, emb_b, A);

    for (int l = 0; l < NL; l++) {
        if (l == 0)
            k_conv<false><<<NN / 32, 256, 0, stream>>>(A, nullptr, WfC, dinv, B);
        else
            k_conv<true><<<NN / 32, 256, 0, stream>>>(A, bnss, WfC + l * 16384, dinv, B);
        k_gather<<<NN / 16, 256, 0, stream>>>(rowptr, col, dinv, B, conv_b + l * HD, A,
                                              bnsum3 + l * NSTRIPE * 256);
        k_bn_fin<<<1, 128, 0, stream>>>(bnsum3 + l * NSTRIPE * 256,
                                        gamma + l * HD, beta + l * HD, bnss);
    }

    // ---- pooling (BN of last layer fused, no atomics, float out) ----
    k_pool_g<<<NG, 128, 0, stream>>>(A, bnss, gstart, gfeat);

    // ---- MLP head v2 ----
    k_mlp<<<NG / 8, 256, 0, stream>>>(gfeat, w1, b1, w2, b2, w3, b3, out);
}

// Round 10
// 419.464 us; speedup vs baseline: 1.7295x; 1.7295x over previous
//
#include <hip/hip_runtime.h>

#define NN 100000   // nodes
#define NE 600000   // edges
#define NG 4096     // graphs
#define FIN 74
#define HD 128
#define NL 3
#define BN_EPS 1e-5f
#define NSCAN 391   // ceil(NN/256)

typedef __attribute__((ext_vector_type(8))) short short8;
typedef __attribute__((ext_vector_type(4))) float floatx4;
typedef __attribute__((ext_vector_type(8))) unsigned short bf16x8;  // ushort4/8 collide with HIP headers
typedef __attribute__((ext_vector_type(4))) unsigned short bf16x4;

__device__ __forceinline__ unsigned short f2bf(float f) {
    unsigned u = __float_as_uint(f);
    u += 0x7fff + ((u >> 16) & 1);   // round-to-nearest-even
    return (unsigned short)(u >> 16);
}
__device__ __forceinline__ float bf2f(unsigned short u) {
    return __uint_as_float(((unsigned)u) << 16);
}

// ---------------- CSR build ----------------
__global__ __launch_bounds__(256) void k_hist(const int* __restrict__ dst,
                                              int* __restrict__ degi) {
    int e = blockIdx.x * 256 + threadIdx.x;
    if (e < NE) atomicAdd(&degi[dst[e]], 1);
}

__global__ __launch_bounds__(256) void k_scan1(const int* __restrict__ degi,
                                               int* __restrict__ part) {
    __shared__ int s[256];
    int t = threadIdx.x;
    int idx = blockIdx.x * 256 + t;
    s[t] = (idx < NN) ? degi[idx] : 0;
    __syncthreads();
    for (int off = 128; off > 0; off >>= 1) {
        if (t < off) s[t] += s[t + off];
        __syncthreads();
    }
    if (t == 0) part[blockIdx.x] = s[0];
}

__global__ __launch_bounds__(512) void k_scan2(int* __restrict__ part) {
    __shared__ int s[512];
    int t = threadIdx.x;
    s[t] = (t < NSCAN) ? part[t] : 0;
    __syncthreads();
    for (int off = 1; off < 512; off <<= 1) {
        int v = s[t];
        int a = (t >= off) ? s[t - off] : 0;
        __syncthreads();
        s[t] = v + a;
        __syncthreads();
    }
    if (t < NSCAN) part[t] = (t > 0) ? s[t - 1] : 0;  // exclusive
}

// scan3 + dinv fused
__global__ __launch_bounds__(256) void k_scan3(const int* __restrict__ degi,
                                               const int* __restrict__ part,
                                               int* __restrict__ rowptr,
                                               float* __restrict__ dinv) {
    __shared__ int s[256];
    int t = threadIdx.x;
    int idx = blockIdx.x * 256 + t;
    int v = (idx < NN) ? degi[idx] : 0;
    s[t] = v;
    __syncthreads();
    for (int off = 1; off < 256; off <<= 1) {
        int x = s[t];
        int a = (t >= off) ? s[t - off] : 0;
        __syncthreads();
        s[t] = x + a;
        __syncthreads();
    }
    if (idx < NN) {
        rowptr[idx] = part[blockIdx.x] + (s[t] - v);
        dinv[idx] = rsqrtf((float)v + 1.0f);  // +1 self-loop
    }
    if (idx == 0) rowptr[NN] = NE;
}

__global__ __launch_bounds__(256) void k_fill(const int* __restrict__ src,
                                              const int* __restrict__ dst,
                                              const int* __restrict__ rowptr,
                                              int* __restrict__ cursor,
                                              int* __restrict__ col) {
    int e = blockIdx.x * 256 + threadIdx.x;
    if (e >= NE) return;
    int d = dst[e];
    int pos = rowptr[d] + atomicAdd(&cursor[d], 1);
    col[pos] = src[e];
}

// ---------------- graph boundaries from sorted batch ----------------
__global__ __launch_bounds__(256) void k_bounds(const int* __restrict__ batch,
                                                int* __restrict__ gstart) {
    int n = blockIdx.x * 256 + threadIdx.x;
    if (n >= NN) return;
    int b = batch[n];
    int bp = (n == 0) ? -1 : batch[n - 1];
    for (int g = bp + 1; g <= b; g++) gstart[g] = n;
    if (n == NN - 1)
        for (int g = b + 1; g <= NG; g++) gstart[g] = NN;
}

// ---------------- weight fragment pre-pack (bf16), emb + conv fused ----------------
__global__ __launch_bounds__(256) void k_wpack(const float* __restrict__ embW,
                                               const float* __restrict__ convW,
                                               unsigned short* __restrict__ WfE,
                                               unsigned short* __restrict__ WfC) {
    int d = blockIdx.x * 256 + threadIdx.x;
    if (d < 12288) {
        int inner = d & 511, outer = d >> 9;
        int kstep = outer % 3, nt = outer / 3;
        int g = inner >> 7, n = (inner >> 3) & 15, j = inner & 7;
        int k = kstep * 32 + g * 8 + j;
        float v = (k < FIN) ? embW[k * HD + nt * 16 + n] : 0.0f;
        WfE[d] = f2bf(v);
    } else {
        int e = d - 12288;
        if (e >= NL * 16384) return;
        int layer = e >> 14, r = e & 16383;
        int j = r & 7, n = (r >> 3) & 15, g = (r >> 7) & 3, kstep = (r >> 9) & 3, nt = r >> 11;
        int k = kstep * 32 + g * 8 + j;
        WfC[e] = f2bf(convW[layer * 16384 + k * HD + nt * 16 + n]);
    }
}

// ---------------- embedding MFMA: A = relu(x @ W + b), bf16 out ----------------
__global__ __launch_bounds__(256) void k_emb(const float* __restrict__ x,
                                             const unsigned short* __restrict__ Wf,
                                             const float* __restrict__ b,
                                             unsigned short* __restrict__ hA) {
    __shared__ __align__(16) unsigned short As[4224];
    int t = threadIdx.x;
    int n0 = blockIdx.x * 32;
    for (int f = t; f < 3072; f += 256) {
        int m = f / 96, kp = f % 96;
        float v = (kp < FIN) ? x[(n0 + m) * FIN + kp] : 0.0f;
        int kstep = kp >> 5, g = (kp >> 3) & 3, j = kp & 7;
        As[(kstep * 4 + g) * 264 + m * 8 + j] = f2bf(v);
    }
    __syncthreads();
    int lane = t & 63, wv = t >> 6;
    int lanelo = lane & 15, g = lane >> 4;
    floatx4 acc[2][2] = {};
#pragma unroll
    for (int kstep = 0; kstep < 3; kstep++) {
        short8 a0 = *(const short8*)&As[(kstep * 4 + g) * 264 + lanelo * 8];
        short8 a1 = *(const short8*)&As[(kstep * 4 + g) * 264 + 128 + lanelo * 8];
        short8 b0 = *(const short8*)&Wf[(((wv * 2 + 0) * 3 + kstep) * 4 + g) * 128 + lanelo * 8];
        short8 b1 = *(const short8*)&Wf[(((wv * 2 + 1) * 3 + kstep) * 4 + g) * 128 + lanelo * 8];
        acc[0][0] = __builtin_amdgcn_mfma_f32_16x16x32_bf16(a0, b0, acc[0][0], 0, 0, 0);
        acc[0][1] = __builtin_amdgcn_mfma_f32_16x16x32_bf16(a0, b1, acc[0][1], 0, 0, 0);
        acc[1][0] = __builtin_amdgcn_mfma_f32_16x16x32_bf16(a1, b0, acc[1][0], 0, 0, 0);
        acc[1][1] = __builtin_amdgcn_mfma_f32_16x16x32_bf16(a1, b1, acc[1][1], 0, 0, 0);
    }
    __syncthreads();  // reuse As as output tile (stride 132)
#pragma unroll
    for (int ns = 0; ns < 2; ns++) {
        int colc = wv * 32 + ns * 16 + lanelo;
        float bias = b[colc];
#pragma unroll
        for (int ms = 0; ms < 2; ms++)
#pragma unroll
            for (int r = 0; r < 4; r++) {
                int rowl = ms * 16 + g * 4 + r;
                As[rowl * 132 + colc] = f2bf(fmaxf(acc[ms][ns][r] + bias, 0.0f));
            }
    }
    __syncthreads();
#pragma unroll
    for (int i = 0; i < 2; i++) {
        int f = t * 8 + i * 2048;
        int m = f >> 7, c = f & 127;
        bf16x4 lo = *(const bf16x4*)&As[m * 132 + c];
        bf16x4 hi = *(const bf16x4*)&As[m * 132 + c + 4];
        bf16x8 o = {lo.x, lo.y, lo.z, lo.w, hi.x, hi.y, hi.z, hi.w};
        *(bf16x8*)&hA[n0 * HD + f] = o;
    }
}

// ---------------- conv MFMA: B' = (act(A) @ W) * dinv[row], bf16 in/out ----------------
template <bool BN>
__global__ __launch_bounds__(256) void k_conv(const unsigned short* __restrict__ hin,
                                              const float* __restrict__ ss,
                                              const unsigned short* __restrict__ Wf,
                                              const float* __restrict__ dinv,
                                              unsigned short* __restrict__ hw) {
    __shared__ __align__(16) unsigned short As[4224];
    __shared__ float dinvs[32];
    int t = threadIdx.x;
    int n0 = blockIdx.x * 32;
    if (t < 32) dinvs[t] = dinv[n0 + t];
    int f0 = t * 8;
    int k0 = f0 & 127;
    float sc[8], sh[8];
    if (BN) {
        floatx4 s0 = *(const floatx4*)&ss[k0];
        floatx4 s1 = *(const floatx4*)&ss[k0 + 4];
        floatx4 h0 = *(const floatx4*)&ss[HD + k0];
        floatx4 h1 = *(const floatx4*)&ss[HD + k0 + 4];
        sc[0] = s0.x; sc[1] = s0.y; sc[2] = s0.z; sc[3] = s0.w;
        sc[4] = s1.x; sc[5] = s1.y; sc[6] = s1.z; sc[7] = s1.w;
        sh[0] = h0.x; sh[1] = h0.y; sh[2] = h0.z; sh[3] = h0.w;
        sh[4] = h1.x; sh[5] = h1.y; sh[6] = h1.z; sh[7] = h1.w;
    }
    int combo = (k0 >> 5) * 4 + ((k0 >> 3) & 3);
#pragma unroll
    for (int i = 0; i < 2; i++) {
        int f = f0 + i * 2048;
        int m = f >> 7;
        bf16x8 u = *(const bf16x8*)&hin[n0 * HD + f];
        bf16x8 o;
        if (BN) {
#pragma unroll
            for (int jj = 0; jj < 8; jj++) {
                float v = fmaxf(bf2f(u[jj]) * sc[jj] + sh[jj], 0.0f);
                o[jj] = f2bf(v);
            }
        } else {
            o = u;
        }
        *(bf16x8*)&As[combo * 264 + m * 8] = o;
    }
    __syncthreads();
    int lane = t & 63, wv = t >> 6;
    int lanelo = lane & 15, g = lane >> 4;
    floatx4 acc[2][2] = {};
#pragma unroll
    for (int ks = 0; ks < 4; ks++) {
        short8 a0 = *(const short8*)&As[(ks * 4 + g) * 264 + lanelo * 8];
        short8 a1 = *(const short8*)&As[(ks * 4 + g) * 264 + 128 + lanelo * 8];
        short8 b0 = *(const short8*)&Wf[(((wv * 2 + 0) * 4 + ks) * 4 + g) * 128 + lanelo * 8];
        short8 b1 = *(const short8*)&Wf[(((wv * 2 + 1) * 4 + ks) * 4 + g) * 128 + lanelo * 8];
        acc[0][0] = __builtin_amdgcn_mfma_f32_16x16x32_bf16(a0, b0, acc[0][0], 0, 0, 0);
        acc[0][1] = __builtin_amdgcn_mfma_f32_16x16x32_bf16(a0, b1, acc[0][1], 0, 0, 0);
        acc[1][0] = __builtin_amdgcn_mfma_f32_16x16x32_bf16(a1, b0, acc[1][0], 0, 0, 0);
        acc[1][1] = __builtin_amdgcn_mfma_f32_16x16x32_bf16(a1, b1, acc[1][1], 0, 0, 0);
    }
    __syncthreads();  // reuse As as output tile
#pragma unroll
    for (int ms = 0; ms < 2; ms++)
#pragma unroll
        for (int ns = 0; ns < 2; ns++) {
            int colc = wv * 32 + ns * 16 + lanelo;
#pragma unroll
            for (int r = 0; r < 4; r++) {
                int rowl = ms * 16 + g * 4 + r;
                As[rowl * 132 + colc] = f2bf(acc[ms][ns][r] * dinvs[rowl]);
            }
        }
    __syncthreads();
#pragma unroll
    for (int i = 0; i < 2; i++) {
        int f = f0 + i * 2048;
        int m = f >> 7, c = f & 127;
        bf16x4 lo = *(const bf16x4*)&As[m * 132 + c];
        bf16x4 hi = *(const bf16x4*)&As[m * 132 + c + 4];
        bf16x8 o = {lo.x, lo.y, lo.z, lo.w, hi.x, hi.y, hi.z, hi.w};
        *(bf16x8*)&hw[n0 * HD + f] = o;
    }
}

// ---------------- CSR gather (bf16), R8-proven: no barriers, no LDS ----------------
__global__ __launch_bounds__(256) void k_gather(const int* __restrict__ rowptr,
                                                const int* __restrict__ col,
                                                const float* __restrict__ dinv,
                                                const unsigned short* __restrict__ B,
                                                const float* __restrict__ bias,
                                                unsigned short* __restrict__ A) {
    int t = threadIdx.x;
    int n = blockIdx.x * 16 + (t >> 4);  // 16 nodes/block, 16 lanes/node
    int c8 = (t & 15) * 8;
    bf16x8 u = *(const bf16x8*)&B[n * HD + c8];
    float acc[8];
#pragma unroll
    for (int i = 0; i < 8; i++) acc[i] = bf2f(u[i]);
    int j0 = rowptr[n], j1 = rowptr[n + 1];
    int j = j0;
    for (; j + 1 < j1; j += 2) {
        int s0 = col[j], s1 = col[j + 1];
        bf16x8 v0 = *(const bf16x8*)&B[s0 * HD + c8];
        bf16x8 v1 = *(const bf16x8*)&B[s1 * HD + c8];
#pragma unroll
        for (int i = 0; i < 8; i++) acc[i] += bf2f(v0[i]) + bf2f(v1[i]);
    }
    if (j < j1) {
        int s = col[j];
        bf16x8 v = *(const bf16x8*)&B[s * HD + c8];
#pragma unroll
        for (int i = 0; i < 8; i++) acc[i] += bf2f(v[i]);
    }
    float dd = dinv[n];
    floatx4 b0 = *(const floatx4*)&bias[c8];
    floatx4 b1 = *(const floatx4*)&bias[c8 + 4];
    bf16x8 o;
    o[0] = f2bf(acc[0] * dd + b0.x); o[1] = f2bf(acc[1] * dd + b0.y);
    o[2] = f2bf(acc[2] * dd + b0.z); o[3] = f2bf(acc[3] * dd + b0.w);
    o[4] = f2bf(acc[4] * dd + b1.x); o[5] = f2bf(acc[5] * dd + b1.y);
    o[6] = f2bf(acc[6] * dd + b1.z); o[7] = f2bf(acc[7] * dd + b1.w);
    *(bf16x8*)&A[n * HD + c8] = o;
}

// ---------------- BN statistics (bf16 input), per-layer pre-zeroed slice ----------------
__global__ __launch_bounds__(256) void k_bn_stats(const unsigned short* __restrict__ h,
                                                  float* __restrict__ sums) {
    __shared__ float ls[256];
    int t = threadIdx.x;
    ls[t] = 0.0f;
    __syncthreads();
    int c8 = (t & 15) * 8;
    float s[8] = {}, sq[8] = {};
    for (int n = blockIdx.x * 16 + (t >> 4); n < NN; n += gridDim.x * 16) {
        bf16x8 u = *(const bf16x8*)&h[n * HD + c8];
#pragma unroll
        for (int i = 0; i < 8; i++) {
            float v = bf2f(u[i]);
            s[i] += v;
            sq[i] += v * v;
        }
    }
#pragma unroll
    for (int i = 0; i < 8; i++) {
        atomicAdd(&ls[c8 + i], s[i]);
        atomicAdd(&ls[HD + c8 + i], sq[i]);
    }
    __syncthreads();
    atomicAdd(&sums[t], ls[t]);
}

__global__ __launch_bounds__(128) void k_bn_fin(const float* __restrict__ sums,
                                                const float* __restrict__ gamma,
                                                const float* __restrict__ beta,
                                                float* __restrict__ ss) {
    int c = threadIdx.x;
    float inv_n = 1.0f / (float)NN;
    float mu = sums[c] * inv_n;
    float var = sums[HD + c] * inv_n - mu * mu;
    float sc = gamma[c] * rsqrtf(var + BN_EPS);
    ss[c] = sc;
    ss[HD + c] = beta[c] - mu * sc;
}

// ---------------- atomic-free pooling: one block per graph (float gfeat out) ----------------
__global__ __launch_bounds__(128) void k_pool_g(const unsigned short* __restrict__ h,
                                                const float* __restrict__ ss,
                                                const int* __restrict__ gstart,
                                                float* __restrict__ gfeat) {
    int g = blockIdx.x;
    int c = threadIdx.x;
    int n0 = gstart[g], n1 = gstart[g + 1];
    float sc = ss[c], sh = ss[HD + c];
    float s = 0.0f, mx = 0.0f;   // post-ReLU >= 0; 0 matches empty-seg guard
    for (int n = n0; n < n1; n++) {
        float v = fmaxf(bf2f(h[n * HD + c]) * sc + sh, 0.0f);
        s += v;
        mx = fmaxf(mx, v);
    }
    float cntf = (float)(n1 - n0);
    gfeat[g * 256 + c] = s / fmaxf(cntf, 1.0f);
    gfeat[g * 256 + HD + c] = mx;
}

// ---------------- MLP head v2: 8 graphs/block, 256 threads, split-K ----------------
__global__ __launch_bounds__(256) void k_mlp(const float* __restrict__ gfeat,
                                             const float* __restrict__ w1,
                                             const float* __restrict__ b1,
                                             const float* __restrict__ w2,
                                             const float* __restrict__ b2,
                                             const float* __restrict__ w3,
                                             const float* __restrict__ b3,
                                             float* __restrict__ out) {
    __shared__ float gs[8][258];
    __shared__ float p1[8][130];
    __shared__ float hs[8][130];
    __shared__ float p2[3][8][66];
    __shared__ float h2s[8][66];
    __shared__ float ps[64];
    int t = threadIdx.x;
    int g0 = blockIdx.x * 8;
    for (int f = t; f < 2048; f += 256) {
        int gi = f >> 8, k = f & 255;
        gs[gi][k] = gfeat[(g0 + gi) * 256 + k];
    }
    __syncthreads();
    {
        int colc = t & 127, half = t >> 7;
        int kb = half * 128;
        float acc[8] = {};
        for (int k = 0; k < 128; k++) {
            float w = w1[(kb + k) * HD + colc];
#pragma unroll
            for (int gi = 0; gi < 8; gi++) acc[gi] += gs[gi][kb + k] * w;
        }
        if (half == 1) {
#pragma unroll
            for (int gi = 0; gi < 8; gi++) p1[gi][colc] = acc[gi];
        }
        __syncthreads();
        if (half == 0) {
            float bias = b1[colc];
#pragma unroll
            for (int gi = 0; gi < 8; gi++)
                hs[gi][colc] = fmaxf(acc[gi] + p1[gi][colc] + bias, 0.0f);
        }
    }
    __syncthreads();
    {
        int colc = t & 63, q = t >> 6;
        int kb = q * 32;
        float acc[8] = {};
        for (int k = 0; k < 32; k++) {
            float w = w2[(kb + k) * 64 + colc];
#pragma unroll
            for (int gi = 0; gi < 8; gi++) acc[gi] += hs[gi][kb + k] * w;
        }
        if (q > 0) {
#pragma unroll
            for (int gi = 0; gi < 8; gi++) p2[q - 1][gi][colc] = acc[gi];
        }
        __syncthreads();
        if (q == 0) {
            float bias = b2[colc];
#pragma unroll
            for (int gi = 0; gi < 8; gi++)
                h2s[gi][colc] = fmaxf(acc[gi] + p2[0][gi][colc] + p2[1][gi][colc]
                                      + p2[2][gi][colc] + bias, 0.0f);
        }
    }
    __syncthreads();
    if (t < 64) {
        int gi = t >> 3, prt = t & 7;
        float p = 0.0f;
#pragma unroll
        for (int k = 0; k < 8; k++) p += h2s[gi][prt * 8 + k] * w3[prt * 8 + k];
        ps[t] = p;
    }
    __syncthreads();
    if (t < 8) {
        float a = b3[0];
#pragma unroll
        for (int i = 0; i < 8; i++) a += ps[t * 8 + i];
        out[g0 + t] = a;
    }
}

extern "C" void kernel_launch(void* const* d_in, const int* in_sizes, int n_in,
                              void* d_out, int out_size, void* d_ws, size_t ws_size,
                              hipStream_t stream) {
    const float* x      = (const float*)d_in[0];
    const int*   eidx   = (const int*)d_in[1];   // [2, NE]: src then dst
    const int*   batch  = (const int*)d_in[2];
    const float* emb_W  = (const float*)d_in[3];
    const float* emb_b  = (const float*)d_in[4];
    const float* conv_W = (const float*)d_in[5];
    const float* conv_b = (const float*)d_in[6];
    const float* gamma  = (const float*)d_in[7];
    const float* beta   = (const float*)d_in[8];
    const float* w1     = (const float*)d_in[9];
    const float* b1     = (const float*)d_in[10];
    const float* w2     = (const float*)d_in[11];
    const float* b2     = (const float*)d_in[12];
    const float* w3     = (const float*)d_in[13];
    const float* b3     = (const float*)d_in[14];
    float* out = (float*)d_out;

    const int* src = eidx;
    const int* dst = eidx + NE;

    // workspace carve-up — bnsum3 / degi / cursor contiguous for ONE zeroing memset
    unsigned short* A = (unsigned short*)d_ws;       // [NN*HD] bf16
    unsigned short* B = A + NN * HD;                 // [NN*HD] bf16
    float* dinv  = (float*)(B + NN * HD);            // [NN]
    float* bnss  = dinv + NN;                        // [256]
    float* gfeat = bnss + 256;                       // [NG*256] float
    float* bnsum3= gfeat + NG * 256;                 // [NL*256]  (zeroed)
    int*   degi  = (int*)(bnsum3 + NL * 256);        // [NN]      (zeroed)
    int*   cursor= degi + NN;                        // [NN]      (zeroed)
    int*   gstart= cursor + NN;                      // [NG+1]
    int*   rowptr= gstart + NG + 1;                  // [NN+1]
    int*   part  = rowptr + NN + 1;                  // [NSCAN]
    int*   col   = part + NSCAN;                     // [NE]
    unsigned short* WfE = (unsigned short*)(col + NE);  // [12288]
    unsigned short* WfC = WfE + 12288;                  // [3*16384]

    // ---- single zeroing memset: bnsum3 + degi + cursor ----
    (void)hipMemsetAsync(bnsum3, 0,
                         (NL * 256) * sizeof(float) + 2 * NN * sizeof(int), stream);
    k_hist<<<(NE + 255) / 256, 256, 0, stream>>>(dst, degi);
    k_scan1<<<NSCAN, 256, 0, stream>>>(degi, part);
    k_scan2<<<1, 512, 0, stream>>>(part);
    k_scan3<<<NSCAN, 256, 0, stream>>>(degi, part, rowptr, dinv);
    k_fill<<<(NE + 255) / 256, 256, 0, stream>>>(src, dst, rowptr, cursor, col);
    k_bounds<<<(NN + 255) / 256, 256, 0, stream>>>(batch, gstart);
    k_wpack<<<240, 256, 0, stream>>>(emb_W, conv_W, WfE, WfC);

    // ---- embedding (bf16 out) ----
    k_emb<<<NN / 32, 256, 0, stream>>>(x, WfE, emb_b, A);

    for (int l = 0; l < NL; l++) {
        if (l == 0)
            k_conv<false><<<NN / 32, 256, 0, stream>>>(A, nullptr, WfC, dinv, B);
        else
            k_conv<true><<<NN / 32, 256, 0, stream>>>(A, bnss, WfC + l * 16384, dinv, B);
        k_gather<<<NN / 16, 256, 0, stream>>>(rowptr, col, dinv, B, conv_b + l * HD, A);
        k_bn_stats<<<512, 256, 0, stream>>>(A, bnsum3 + l * 256);
        k_bn_fin<<<1, 128, 0, stream>>>(bnsum3 + l * 256,
                                        gamma + l * HD, beta + l * HD, bnss);
    }

    // ---- pooling (BN of last layer fused, no atomics, float out) ----
    k_pool_g<<<NG, 128, 0, stream>>>(A, bnss, gstart, gfeat);

    // ---- MLP head v2 ----
    k_mlp<<<NG / 8, 256, 0, stream>>>(gfeat, w1, b1, w2, b2, w3, b3, out);
}

// Round 11
// 410.529 us; speedup vs baseline: 1.7671x; 1.0218x over previous
//
#include <hip/hip_runtime.h>

#define NN 100000   // nodes
#define NE 600000   // edges
#define NG 4096     // graphs
#define FIN 74
#define HD 128
#define NL 3
#define BN_EPS 1e-5f
#define NSCAN 391   // ceil(NN/256)
#define NHISTB 2344 // ceil(NE/256)

typedef __attribute__((ext_vector_type(8))) short short8;
typedef __attribute__((ext_vector_type(4))) float floatx4;
typedef __attribute__((ext_vector_type(8))) unsigned short bf16x8;  // ushort4/8 collide with HIP headers
typedef __attribute__((ext_vector_type(4))) unsigned short bf16x4;

__device__ __forceinline__ unsigned short f2bf(float f) {
    unsigned u = __float_as_uint(f);
    u += 0x7fff + ((u >> 16) & 1);   // round-to-nearest-even
    return (unsigned short)(u >> 16);
}
__device__ __forceinline__ float bf2f(unsigned short u) {
    return __uint_as_float(((unsigned)u) << 16);
}

// ---------------- fused preprocessing: hist | bounds | wpack ----------------
__global__ __launch_bounds__(256) void k_pre(const int* __restrict__ dst,
                                             int* __restrict__ degi,
                                             const int* __restrict__ batch,
                                             int* __restrict__ gstart,
                                             const float* __restrict__ embW,
                                             const float* __restrict__ convW,
                                             unsigned short* __restrict__ WfE,
                                             unsigned short* __restrict__ WfC) {
    int blk = blockIdx.x;
    int t = threadIdx.x;
    if (blk < NHISTB) {
        int e = blk * 256 + t;
        if (e < NE) atomicAdd(&degi[dst[e]], 1);
    } else if (blk < NHISTB + NSCAN) {
        int n = (blk - NHISTB) * 256 + t;
        if (n >= NN) return;
        int b = batch[n];
        int bp = (n == 0) ? -1 : batch[n - 1];
        for (int g = bp + 1; g <= b; g++) gstart[g] = n;
        if (n == NN - 1)
            for (int g = b + 1; g <= NG; g++) gstart[g] = NN;
    } else {
        int d = (blk - NHISTB - NSCAN) * 256 + t;
        if (d < 12288) {
            int inner = d & 511, outer = d >> 9;
            int kstep = outer % 3, nt = outer / 3;
            int g = inner >> 7, n = (inner >> 3) & 15, j = inner & 7;
            int k = kstep * 32 + g * 8 + j;
            float v = (k < FIN) ? embW[k * HD + nt * 16 + n] : 0.0f;
            WfE[d] = f2bf(v);
        } else {
            int e = d - 12288;
            if (e >= NL * 16384) return;
            int layer = e >> 14, r = e & 16383;
            int j = r & 7, n = (r >> 3) & 15, g = (r >> 7) & 3, kstep = (r >> 9) & 3, nt = r >> 11;
            int k = kstep * 32 + g * 8 + j;
            WfC[e] = f2bf(convW[layer * 16384 + k * HD + nt * 16 + n]);
        }
    }
}

__global__ __launch_bounds__(256) void k_scan1(const int* __restrict__ degi,
                                               int* __restrict__ part) {
    __shared__ int s[256];
    int t = threadIdx.x;
    int idx = blockIdx.x * 256 + t;
    s[t] = (idx < NN) ? degi[idx] : 0;
    __syncthreads();
    for (int off = 128; off > 0; off >>= 1) {
        if (t < off) s[t] += s[t + off];
        __syncthreads();
    }
    if (t == 0) part[blockIdx.x] = s[0];
}

__global__ __launch_bounds__(512) void k_scan2(int* __restrict__ part) {
    __shared__ int s[512];
    int t = threadIdx.x;
    s[t] = (t < NSCAN) ? part[t] : 0;
    __syncthreads();
    for (int off = 1; off < 512; off <<= 1) {
        int v = s[t];
        int a = (t >= off) ? s[t - off] : 0;
        __syncthreads();
        s[t] = v + a;
        __syncthreads();
    }
    if (t < NSCAN) part[t] = (t > 0) ? s[t - 1] : 0;  // exclusive
}

// scan3 + dinv fused
__global__ __launch_bounds__(256) void k_scan3(const int* __restrict__ degi,
                                               const int* __restrict__ part,
                                               int* __restrict__ rowptr,
                                               float* __restrict__ dinv) {
    __shared__ int s[256];
    int t = threadIdx.x;
    int idx = blockIdx.x * 256 + t;
    int v = (idx < NN) ? degi[idx] : 0;
    s[t] = v;
    __syncthreads();
    for (int off = 1; off < 256; off <<= 1) {
        int x = s[t];
        int a = (t >= off) ? s[t - off] : 0;
        __syncthreads();
        s[t] = x + a;
        __syncthreads();
    }
    if (idx < NN) {
        rowptr[idx] = part[blockIdx.x] + (s[t] - v);
        dinv[idx] = rsqrtf((float)v + 1.0f);  // +1 self-loop
    }
    if (idx == 0) rowptr[NN] = NE;
}

__global__ __launch_bounds__(256) void k_fill(const int* __restrict__ src,
                                              const int* __restrict__ dst,
                                              const int* __restrict__ rowptr,
                                              int* __restrict__ cursor,
                                              int* __restrict__ col) {
    int e = blockIdx.x * 256 + threadIdx.x;
    if (e >= NE) return;
    int d = dst[e];
    int pos = rowptr[d] + atomicAdd(&cursor[d], 1);
    col[pos] = src[e];
}

// ---------------- embedding MFMA: A = relu(x @ W + b), bf16 out ----------------
__global__ __launch_bounds__(256) void k_emb(const float* __restrict__ x,
                                             const unsigned short* __restrict__ Wf,
                                             const float* __restrict__ b,
                                             unsigned short* __restrict__ hA) {
    __shared__ __align__(16) unsigned short As[4224];
    int t = threadIdx.x;
    int n0 = blockIdx.x * 32;
    for (int f = t; f < 3072; f += 256) {
        int m = f / 96, kp = f % 96;
        float v = (kp < FIN) ? x[(n0 + m) * FIN + kp] : 0.0f;
        int kstep = kp >> 5, g = (kp >> 3) & 3, j = kp & 7;
        As[(kstep * 4 + g) * 264 + m * 8 + j] = f2bf(v);
    }
    __syncthreads();
    int lane = t & 63, wv = t >> 6;
    int lanelo = lane & 15, g = lane >> 4;
    floatx4 acc[2][2] = {};
#pragma unroll
    for (int kstep = 0; kstep < 3; kstep++) {
        short8 a0 = *(const short8*)&As[(kstep * 4 + g) * 264 + lanelo * 8];
        short8 a1 = *(const short8*)&As[(kstep * 4 + g) * 264 + 128 + lanelo * 8];
        short8 b0 = *(const short8*)&Wf[(((wv * 2 + 0) * 3 + kstep) * 4 + g) * 128 + lanelo * 8];
        short8 b1 = *(const short8*)&Wf[(((wv * 2 + 1) * 3 + kstep) * 4 + g) * 128 + lanelo * 8];
        acc[0][0] = __builtin_amdgcn_mfma_f32_16x16x32_bf16(a0, b0, acc[0][0], 0, 0, 0);
        acc[0][1] = __builtin_amdgcn_mfma_f32_16x16x32_bf16(a0, b1, acc[0][1], 0, 0, 0);
        acc[1][0] = __builtin_amdgcn_mfma_f32_16x16x32_bf16(a1, b0, acc[1][0], 0, 0, 0);
        acc[1][1] = __builtin_amdgcn_mfma_f32_16x16x32_bf16(a1, b1, acc[1][1], 0, 0, 0);
    }
    __syncthreads();  // reuse As as output tile (stride 132)
#pragma unroll
    for (int ns = 0; ns < 2; ns++) {
        int colc = wv * 32 + ns * 16 + lanelo;
        float bias = b[colc];
#pragma unroll
        for (int ms = 0; ms < 2; ms++)
#pragma unroll
            for (int r = 0; r < 4; r++) {
                int rowl = ms * 16 + g * 4 + r;
                As[rowl * 132 + colc] = f2bf(fmaxf(acc[ms][ns][r] + bias, 0.0f));
            }
    }
    __syncthreads();
#pragma unroll
    for (int i = 0; i < 2; i++) {
        int f = t * 8 + i * 2048;
        int m = f >> 7, c = f & 127;
        bf16x4 lo = *(const bf16x4*)&As[m * 132 + c];
        bf16x4 hi = *(const bf16x4*)&As[m * 132 + c + 4];
        bf16x8 o = {lo.x, lo.y, lo.z, lo.w, hi.x, hi.y, hi.z, hi.w};
        *(bf16x8*)&hA[n0 * HD + f] = o;
    }
}

// ---------------- conv MFMA: B' = (act(A) @ W) * dinv[row], bf16 in/out ----------------
// BN=true: affine computed inline from bnsum/gamma/beta (bn_fin fused)
template <bool BN>
__global__ __launch_bounds__(256) void k_conv(const unsigned short* __restrict__ hin,
                                              const float* __restrict__ bnsum,
                                              const float* __restrict__ gamma,
                                              const float* __restrict__ beta,
                                              const unsigned short* __restrict__ Wf,
                                              const float* __restrict__ dinv,
                                              unsigned short* __restrict__ hw) {
    __shared__ __align__(16) unsigned short As[4224];
    __shared__ float dinvs[32];
    int t = threadIdx.x;
    int n0 = blockIdx.x * 32;
    if (t < 32) dinvs[t] = dinv[n0 + t];
    int f0 = t * 8;
    int k0 = f0 & 127;
    float sc[8], sh[8];
    if (BN) {
        const float inv_n = 1.0f / (float)NN;
#pragma unroll
        for (int jj = 0; jj < 8; jj++) {
            int k = k0 + jj;
            float mu = bnsum[k] * inv_n;
            float var = bnsum[HD + k] * inv_n - mu * mu;
            float s = gamma[k] * rsqrtf(var + BN_EPS);
            sc[jj] = s;
            sh[jj] = beta[k] - mu * s;
        }
    }
    int combo = (k0 >> 5) * 4 + ((k0 >> 3) & 3);
#pragma unroll
    for (int i = 0; i < 2; i++) {
        int f = f0 + i * 2048;
        int m = f >> 7;
        bf16x8 u = *(const bf16x8*)&hin[n0 * HD + f];
        bf16x8 o;
        if (BN) {
#pragma unroll
            for (int jj = 0; jj < 8; jj++) {
                float v = fmaxf(bf2f(u[jj]) * sc[jj] + sh[jj], 0.0f);
                o[jj] = f2bf(v);
            }
        } else {
            o = u;
        }
        *(bf16x8*)&As[combo * 264 + m * 8] = o;
    }
    __syncthreads();
    int lane = t & 63, wv = t >> 6;
    int lanelo = lane & 15, g = lane >> 4;
    floatx4 acc[2][2] = {};
#pragma unroll
    for (int ks = 0; ks < 4; ks++) {
        short8 a0 = *(const short8*)&As[(ks * 4 + g) * 264 + lanelo * 8];
        short8 a1 = *(const short8*)&As[(ks * 4 + g) * 264 + 128 + lanelo * 8];
        short8 b0 = *(const short8*)&Wf[(((wv * 2 + 0) * 4 + ks) * 4 + g) * 128 + lanelo * 8];
        short8 b1 = *(const short8*)&Wf[(((wv * 2 + 1) * 4 + ks) * 4 + g) * 128 + lanelo * 8];
        acc[0][0] = __builtin_amdgcn_mfma_f32_16x16x32_bf16(a0, b0, acc[0][0], 0, 0, 0);
        acc[0][1] = __builtin_amdgcn_mfma_f32_16x16x32_bf16(a0, b1, acc[0][1], 0, 0, 0);
        acc[1][0] = __builtin_amdgcn_mfma_f32_16x16x32_bf16(a1, b0, acc[1][0], 0, 0, 0);
        acc[1][1] = __builtin_amdgcn_mfma_f32_16x16x32_bf16(a1, b1, acc[1][1], 0, 0, 0);
    }
    __syncthreads();  // reuse As as output tile
#pragma unroll
    for (int ms = 0; ms < 2; ms++)
#pragma unroll
        for (int ns = 0; ns < 2; ns++) {
            int colc = wv * 32 + ns * 16 + lanelo;
#pragma unroll
            for (int r = 0; r < 4; r++) {
                int rowl = ms * 16 + g * 4 + r;
                As[rowl * 132 + colc] = f2bf(acc[ms][ns][r] * dinvs[rowl]);
            }
        }
    __syncthreads();
#pragma unroll
    for (int i = 0; i < 2; i++) {
        int f = f0 + i * 2048;
        int m = f >> 7, c = f & 127;
        bf16x4 lo = *(const bf16x4*)&As[m * 132 + c];
        bf16x4 hi = *(const bf16x4*)&As[m * 132 + c + 4];
        bf16x8 o = {lo.x, lo.y, lo.z, lo.w, hi.x, hi.y, hi.z, hi.w};
        *(bf16x8*)&hw[n0 * HD + f] = o;
    }
}

// ---------------- CSR gather (bf16), R8-proven: no barriers, no LDS ----------------
__global__ __launch_bounds__(256) void k_gather(const int* __restrict__ rowptr,
                                                const int* __restrict__ col,
                                                const float* __restrict__ dinv,
                                                const unsigned short* __restrict__ B,
                                                const float* __restrict__ bias,
                                                unsigned short* __restrict__ A) {
    int t = threadIdx.x;
    int n = blockIdx.x * 16 + (t >> 4);  // 16 nodes/block, 16 lanes/node
    int c8 = (t & 15) * 8;
    bf16x8 u = *(const bf16x8*)&B[n * HD + c8];
    float acc[8];
#pragma unroll
    for (int i = 0; i < 8; i++) acc[i] = bf2f(u[i]);
    int j0 = rowptr[n], j1 = rowptr[n + 1];
    int j = j0;
    for (; j + 1 < j1; j += 2) {
        int s0 = col[j], s1 = col[j + 1];
        bf16x8 v0 = *(const bf16x8*)&B[s0 * HD + c8];
        bf16x8 v1 = *(const bf16x8*)&B[s1 * HD + c8];
#pragma unroll
        for (int i = 0; i < 8; i++) acc[i] += bf2f(v0[i]) + bf2f(v1[i]);
    }
    if (j < j1) {
        int s = col[j];
        bf16x8 v = *(const bf16x8*)&B[s * HD + c8];
#pragma unroll
        for (int i = 0; i < 8; i++) acc[i] += bf2f(v[i]);
    }
    float dd = dinv[n];
    floatx4 b0 = *(const floatx4*)&bias[c8];
    floatx4 b1 = *(const floatx4*)&bias[c8 + 4];
    bf16x8 o;
    o[0] = f2bf(acc[0] * dd + b0.x); o[1] = f2bf(acc[1] * dd + b0.y);
    o[2] = f2bf(acc[2] * dd + b0.z); o[3] = f2bf(acc[3] * dd + b0.w);
    o[4] = f2bf(acc[4] * dd + b1.x); o[5] = f2bf(acc[5] * dd + b1.y);
    o[6] = f2bf(acc[6] * dd + b1.z); o[7] = f2bf(acc[7] * dd + b1.w);
    *(bf16x8*)&A[n * HD + c8] = o;
}

// ---------------- BN statistics (bf16 input), per-layer pre-zeroed slice ----------------
__global__ __launch_bounds__(256) void k_bn_stats(const unsigned short* __restrict__ h,
                                                  float* __restrict__ sums) {
    __shared__ float ls[256];
    int t = threadIdx.x;
    ls[t] = 0.0f;
    __syncthreads();
    int c8 = (t & 15) * 8;
    float s[8] = {}, sq[8] = {};
    for (int n = blockIdx.x * 16 + (t >> 4); n < NN; n += gridDim.x * 16) {
        bf16x8 u = *(const bf16x8*)&h[n * HD + c8];
#pragma unroll
        for (int i = 0; i < 8; i++) {
            float v = bf2f(u[i]);
            s[i] += v;
            sq[i] += v * v;
        }
    }
#pragma unroll
    for (int i = 0; i < 8; i++) {
        atomicAdd(&ls[c8 + i], s[i]);
        atomicAdd(&ls[HD + c8 + i], sq[i]);
    }
    __syncthreads();
    atomicAdd(&sums[t], ls[t]);
}

// ---------------- pooling: one block per graph; BN affine computed inline ----------------
__global__ __launch_bounds__(128) void k_pool_g(const unsigned short* __restrict__ h,
                                                const float* __restrict__ bnsum,
                                                const float* __restrict__ gamma,
                                                const float* __restrict__ beta,
                                                const int* __restrict__ gstart,
                                                float* __restrict__ gfeat) {
    int g = blockIdx.x;
    int c = threadIdx.x;
    int n0 = gstart[g], n1 = gstart[g + 1];
    const float inv_n = 1.0f / (float)NN;
    float mu = bnsum[c] * inv_n;
    float var = bnsum[HD + c] * inv_n - mu * mu;
    float sc = gamma[c] * rsqrtf(var + BN_EPS);
    float sh = beta[c] - mu * sc;
    float s = 0.0f, mx = 0.0f;   // post-ReLU >= 0; 0 matches empty-seg guard
    for (int n = n0; n < n1; n++) {
        float v = fmaxf(bf2f(h[n * HD + c]) * sc + sh, 0.0f);
        s += v;
        mx = fmaxf(mx, v);
    }
    float cntf = (float)(n1 - n0);
    gfeat[g * 256 + c] = s / fmaxf(cntf, 1.0f);
    gfeat[g * 256 + HD + c] = mx;
}

// ---------------- MLP head v2: 8 graphs/block, 256 threads, split-K ----------------
__global__ __launch_bounds__(256) void k_mlp(const float* __restrict__ gfeat,
                                             const float* __restrict__ w1,
                                             const float* __restrict__ b1,
                                             const float* __restrict__ w2,
                                             const float* __restrict__ b2,
                                             const float* __restrict__ w3,
                                             const float* __restrict__ b3,
                                             float* __restrict__ out) {
    __shared__ float gs[8][258];
    __shared__ float p1[8][130];
    __shared__ float hs[8][130];
    __shared__ float p2[3][8][66];
    __shared__ float h2s[8][66];
    __shared__ float ps[64];
    int t = threadIdx.x;
    int g0 = blockIdx.x * 8;
    for (int f = t; f < 2048; f += 256) {
        int gi = f >> 8, k = f & 255;
        gs[gi][k] = gfeat[(g0 + gi) * 256 + k];
    }
    __syncthreads();
    {
        int colc = t & 127, half = t >> 7;
        int kb = half * 128;
        float acc[8] = {};
        for (int k = 0; k < 128; k++) {
            float w = w1[(kb + k) * HD + colc];
#pragma unroll
            for (int gi = 0; gi < 8; gi++) acc[gi] += gs[gi][kb + k] * w;
        }
        if (half == 1) {
#pragma unroll
            for (int gi = 0; gi < 8; gi++) p1[gi][colc] = acc[gi];
        }
        __syncthreads();
        if (half == 0) {
            float bias = b1[colc];
#pragma unroll
            for (int gi = 0; gi < 8; gi++)
                hs[gi][colc] = fmaxf(acc[gi] + p1[gi][colc] + bias, 0.0f);
        }
    }
    __syncthreads();
    {
        int colc = t & 63, q = t >> 6;
        int kb = q * 32;
        float acc[8] = {};
        for (int k = 0; k < 32; k++) {
            float w = w2[(kb + k) * 64 + colc];
#pragma unroll
            for (int gi = 0; gi < 8; gi++) acc[gi] += hs[gi][kb + k] * w;
        }
        if (q > 0) {
#pragma unroll
            for (int gi = 0; gi < 8; gi++) p2[q - 1][gi][colc] = acc[gi];
        }
        __syncthreads();
        if (q == 0) {
            float bias = b2[colc];
#pragma unroll
            for (int gi = 0; gi < 8; gi++)
                h2s[gi][colc] = fmaxf(acc[gi] + p2[0][gi][colc] + p2[1][gi][colc]
                                      + p2[2][gi][colc] + bias, 0.0f);
        }
    }
    __syncthreads();
    if (t < 64) {
        int gi = t >> 3, prt = t & 7;
        float p = 0.0f;
#pragma unroll
        for (int k = 0; k < 8; k++) p += h2s[gi][prt * 8 + k] * w3[prt * 8 + k];
        ps[t] = p;
    }
    __syncthreads();
    if (t < 8) {
        float a = b3[0];
#pragma unroll
        for (int i = 0; i < 8; i++) a += ps[t * 8 + i];
        out[g0 + t] = a;
    }
}

extern "C" void kernel_launch(void* const* d_in, const int* in_sizes, int n_in,
                              void* d_out, int out_size, void* d_ws, size_t ws_size,
                              hipStream_t stream) {
    const float* x      = (const float*)d_in[0];
    const int*   eidx   = (const int*)d_in[1];   // [2, NE]: src then dst
    const int*   batch  = (const int*)d_in[2];
    const float* emb_W  = (const float*)d_in[3];
    const float* emb_b  = (const float*)d_in[4];
    const float* conv_W = (const float*)d_in[5];
    const float* conv_b = (const float*)d_in[6];
    const float* gamma  = (const float*)d_in[7];
    const float* beta   = (const float*)d_in[8];
    const float* w1     = (const float*)d_in[9];
    const float* b1     = (const float*)d_in[10];
    const float* w2     = (const float*)d_in[11];
    const float* b2     = (const float*)d_in[12];
    const float* w3     = (const float*)d_in[13];
    const float* b3     = (const float*)d_in[14];
    float* out = (float*)d_out;

    const int* src = eidx;
    const int* dst = eidx + NE;

    // workspace carve-up — bnsum3 / degi / cursor contiguous for ONE zeroing memset
    unsigned short* A = (unsigned short*)d_ws;       // [NN*HD] bf16
    unsigned short* B = A + NN * HD;                 // [NN*HD] bf16
    float* dinv  = (float*)(B + NN * HD);            // [NN]
    float* gfeat = dinv + NN;                        // [NG*256] float
    float* bnsum3= gfeat + NG * 256;                 // [NL*256]  (zeroed)
    int*   degi  = (int*)(bnsum3 + NL * 256);        // [NN]      (zeroed)
    int*   cursor= degi + NN;                        // [NN]      (zeroed)
    int*   gstart= cursor + NN;                      // [NG+1]
    int*   rowptr= gstart + NG + 1;                  // [NN+1]
    int*   part  = rowptr + NN + 1;                  // [NSCAN]
    int*   col   = part + NSCAN;                     // [NE]
    unsigned short* WfE = (unsigned short*)(col + NE);  // [12288]
    unsigned short* WfC = WfE + 12288;                  // [3*16384]

    // ---- single zeroing memset: bnsum3 + degi + cursor ----
    (void)hipMemsetAsync(bnsum3, 0,
                         (NL * 256) * sizeof(float) + 2 * NN * sizeof(int), stream);
    // fused hist | bounds | wpack
    k_pre<<<NHISTB + NSCAN + 240, 256, 0, stream>>>(dst, degi, batch, gstart,
                                                    emb_W, conv_W, WfE, WfC);
    k_scan1<<<NSCAN, 256, 0, stream>>>(degi, part);
    k_scan2<<<1, 512, 0, stream>>>(part);
    k_scan3<<<NSCAN, 256, 0, stream>>>(degi, part, rowptr, dinv);
    k_fill<<<(NE + 255) / 256, 256, 0, stream>>>(src, dst, rowptr, cursor, col);

    // ---- embedding (bf16 out) ----
    k_emb<<<NN / 32, 256, 0, stream>>>(x, WfE, emb_b, A);

    for (int l = 0; l < NL; l++) {
        if (l == 0)
            k_conv<false><<<NN / 32, 256, 0, stream>>>(A, nullptr, nullptr, nullptr,
                                                       WfC, dinv, B);
        else
            k_conv<true><<<NN / 32, 256, 0, stream>>>(A, bnsum3 + (l - 1) * 256,
                                                      gamma + (l - 1) * HD,
                                                      beta + (l - 1) * HD,
                                                      WfC + l * 16384, dinv, B);
        k_gather<<<NN / 16, 256, 0, stream>>>(rowptr, col, dinv, B, conv_b + l * HD, A);
        k_bn_stats<<<512, 256, 0, stream>>>(A, bnsum3 + l * 256);
    }

    // ---- pooling (BN of last layer computed inline, no atomics, float out) ----
    k_pool_g<<<NG, 128, 0, stream>>>(A, bnsum3 + 2 * 256, gamma + 2 * HD, beta + 2 * HD,
                                     gstart, gfeat);

    // ---- MLP head v2 ----
    k_mlp<<<NG / 8, 256, 0, stream>>>(gfeat, w1, b1, w2, b2, w3, b3, out);
}